// Round 11
// baseline (124.425 us; speedup 1.0000x reference)
//
#include <hip/hip_runtime.h>

#define EDGES 800000
#define NGRP 12500          // total 64-edge groups
#define GRID 768            // 3 blocks/CU x 256 CU = measured resident capacity

#define LOG2E 1.44269504089f
#define LN2   0.69314718056f

typedef __attribute__((ext_vector_type(8))) short short8;
typedef __attribute__((ext_vector_type(4))) float f32x4;

__device__ __forceinline__ unsigned short f2bf(float f) {   // cold path (weights)
    union { float f; unsigned u; } c; c.f = f;
    return (unsigned short)((c.u + 0x7FFFu + ((c.u >> 16) & 1u)) >> 16);
}

// packed bf16 pair: one v_cvt_pk_bf16_f32 -> u32 word {lo, hi}
__device__ __forceinline__ unsigned pk2(float lo, float hi) {
    unsigned r;
    asm("v_cvt_pk_bf16_f32 %0, %1, %2" : "=v"(r) : "v"(lo), "v"(hi));
    return r;
}

// u = t*log2e (weights prescaled). Returns log2e*silu(t) = u*sigmoid(t).
__device__ __forceinline__ float silu_pre(float u) {
    return u * __builtin_amdgcn_rcpf(1.0f + __builtin_amdgcn_exp2f(-u));
}

// Barrier waiting only on LDS ops (atomics may stay in flight) — R9 win.
__device__ __forceinline__ void barrier_lds() {
    asm volatile("s_waitcnt lgkmcnt(0)\n\ts_barrier" ::: "memory");
}

// fast atan2: A&S 4.4.49 poly, |err| <= ~1e-5; atan2(0,0) -> 0 like numpy
__device__ __forceinline__ float fast_atan2f(float y, float x) {
    float ax = __builtin_fabsf(x), ay = __builtin_fabsf(y);
    float mx = fmaxf(ax, ay), mn = fminf(ax, ay);
    float z  = mn * __builtin_amdgcn_rcpf(mx);
    float z2 = z * z;
    float p  = fmaf(z2, 0.0208351f, -0.0851330f);
    p = fmaf(z2, p, 0.1801410f);
    p = fmaf(z2, p, -0.3302995f);
    p = fmaf(z2, p, 0.9998660f);
    float t = z * p;
    t = (ay > ax)   ? 1.57079632679f - t : t;
    t = (x < 0.0f)  ? 3.14159265359f - t : t;
    t = (y < 0.0f)  ? -t : t;
    return (mx > 0.0f) ? t : 0.0f;
}

// flag: 1 = int32 edge_index layout, 0 = int64 (low words at even positions)
__global__ void detect_idx_kernel(const int* __restrict__ ei, int* __restrict__ flag) {
    int t = threadIdx.x;
    int v = 0;
    for (int k = t; k < 2048; k += 64) v |= ei[2 * k + 1];
    unsigned long long m = __ballot(v != 0);
    if (t == 0) flag[0] = (m != 0ull) ? 1 : 0;
}

__global__ __launch_bounds__(256, 4) void gnn_mfma_kernel(
    const float* __restrict__ x, const float* __restrict__ theta,
    const float* __restrict__ H, const int* __restrict__ ei,
    const float* __restrict__ W1, const float* __restrict__ b1,
    const float* __restrict__ W2, const float* __restrict__ b2,
    const float* __restrict__ W3, const float* __restrict__ b3,
    float* __restrict__ out, const int* __restrict__ flag)
{
    __shared__ unsigned short Xs[256 * 32];  // 16 KB: 256 rows x 32 bf16, chunk-swizzled
    __shared__ int idxs[256];                // out base per row
    // Weight fragments, lane-indexed (conflict-free ds_read_b128).
    // f: 0..3=W1, 4..11=W2[mt][s], 12..13=W3.
    __shared__ short8 Wlds[14][64];          // 14 KB

    const int t    = threadIdx.x;
    const int lane = t & 63;
    const int wv   = t >> 6;
    const int g16  = lane >> 4;
    const int l15  = lane & 15;
    const bool idx32 = (flag[0] != 0);

    // zero the two K-pad chunks of every row once (sw = row&3 is row-invariant)
    {
        short8 zz;
        #pragma unroll
        for (int q = 0; q < 8; ++q) zz[q] = 0;
        unsigned short* bp = &Xs[t * 32];
        int sw = t & 3;
        *(short8*)(bp + ((2 ^ sw) << 3)) = zz;
        *(short8*)(bp + ((3 ^ sw) << 3)) = zz;
    }

    // ---------- weight fragments -> LDS (cold; wave 0 only), PRESCALED ----------
    // W1,b1 *= log2e ; W2 unchanged (ln2*log2e = 1) ; b2 *= log2e ;
    // W3 *= ln2 ; b3 unchanged.  (verified exact R5/R7/R9/R10)
    if (wv == 0) {
        #pragma unroll
        for (int nt = 0; nt < 4; ++nt) {
            short8 v;
            #pragma unroll
            for (int j = 0; j < 8; ++j) {
                int k = 8 * g16 + j;
                int h = nt * 16 + l15;
                float w = 0.0f;
                if (k < 10)       w = W1[k * 64 + h] * LOG2E;
                else if (k == 10) w = b1[h] * LOG2E;
                v[j] = (short)f2bf(w);
            }
            Wlds[nt][lane] = v;
        }
        // physical k-slot p = 32s + 8g + j holds logical unit
        //   lambda(p) = 16*(2s + (j>>2)) + 4g + (j&3)
        #pragma unroll
        for (int mt = 0; mt < 4; ++mt) {
            #pragma unroll
            for (int s = 0; s < 2; ++s) {
                short8 v;
                #pragma unroll
                for (int j = 0; j < 8; ++j) {
                    int h1 = 16 * (2 * s + (j >> 2)) + 4 * g16 + (j & 3);
                    int h2 = 16 * mt + l15;
                    v[j] = (short)f2bf(W2[h1 * 64 + h2]);
                }
                Wlds[4 + 2 * mt + s][lane] = v;
            }
        }
        #pragma unroll
        for (int s = 0; s < 2; ++s) {
            short8 v;
            #pragma unroll
            for (int j = 0; j < 8; ++j) {
                int h2 = 16 * (2 * s + (j >> 2)) + 4 * g16 + (j & 3);
                float w = (l15 < 2) ? W3[h2 * 2 + l15] * LN2 : 0.0f;
                v[j] = (short)f2bf(w);
            }
            Wlds[12 + s][lane] = v;
        }
    }
    f32x4 bias2[4];
    #pragma unroll
    for (int mt = 0; mt < 4; ++mt) {
        #pragma unroll
        for (int r = 0; r < 4; ++r)
            bias2[mt][r] = b2[16 * mt + 4 * g16 + r] * LOG2E;
    }
    f32x4 c3i;
    #pragma unroll
    for (int r = 0; r < 4; ++r) {
        int o = 4 * g16 + r;
        c3i[r] = (o == 0) ? b3[0] : ((o == 1) ? b3[1] : 0.0f);
    }
    barrier_lds();

    // ---------- persistent-block group loop: grid matches residency ----------
    for (int grp = blockIdx.x; grp < NGRP; grp += GRID) {
        const int e0 = grp * 64;

        // ---------- phase 1: geometry, one (edge,slot) row per thread ----------
        {
            int el = t >> 2, slot = t & 3;
            int e = e0 + el;
            int i, j;
            if (idx32) { i = ei[e];     j = ei[EDGES + e]; }
            else       { i = ei[2 * e]; j = ei[2 * EDGES + 2 * e]; }

            float dx0 = x[3 * j + 0] - x[3 * i + 0];
            float dx1 = x[3 * j + 1] - x[3 * i + 1];
            float dz  = x[3 * j + 2] - x[3 * i + 2];
            float rxy2 = dx0 * dx0 + dx1 * dx1;
            float r3d  = __builtin_amdgcn_sqrtf(rxy2 + dz * dz);
            float rxy  = __builtin_amdgcn_sqrtf(rxy2);
            float phi  = fast_atan2f(dx1, dx0);
            float ti = theta[i], tj = theta[j];
            float dphi = phi - ti;
            float sdp = __sinf(dphi), cdp = __cosf(dphi);
            float dt2 = 2.0f * (tj - ti);
            float s2 = __sinf(dt2), c2 = __cosf(dt2);
            float g7 = (dz > 0.0f) ? s2 : ((dz < 0.0f) ? -s2 : 0.0f);

            float2 hv = *(const float2*)&H[((long)j * 4 + slot) * 2];
            float in0 = c2 * hv.x - s2 * hv.y;
            float in1 = s2 * hv.x + c2 * hv.y;

            union { short8 s8; unsigned u[4]; } A, B;
            A.u[0] = pk2(in0, in1);
            A.u[1] = pk2(r3d, rxy);
            A.u[2] = pk2(dz, sdp);
            A.u[3] = pk2(cdp, s2);
            B.u[0] = pk2(c2, g7);
            B.u[1] = 0x00003F80u;   // {1.0bf, 0}
            B.u[2] = 0; B.u[3] = 0;

            int row = t;
            unsigned short* bp = &Xs[row * 32];
            int sw = row & 3;  // chunk XOR swizzle; chunks 2^sw,3^sw stay zero
            *(short8*)(bp + ((0 ^ sw) << 3)) = A.s8;
            *(short8*)(bp + ((1 ^ sw) << 3)) = B.s8;
            idxs[row] = i * 8 + slot * 2;
        }
        barrier_lds();

        // ---------- phase 2: 4 M-tiles of 16 edge-rows per wave ----------
        #pragma unroll
        for (int tt = 0; tt < 4; ++tt) {
            int row = wv * 64 + tt * 16 + l15;
            short8 xb = *(const short8*)(&Xs[row * 32] + ((g16 ^ (row & 3)) << 3));

            f32x4 z4 = {0.0f, 0.0f, 0.0f, 0.0f};
            f32x4 c1[4];
            #pragma unroll
            for (int nt = 0; nt < 4; ++nt)
                c1[nt] = __builtin_amdgcn_mfma_f32_16x16x32_bf16(Wlds[nt][lane], xb, z4, 0, 0, 0);

            // word w of pb[s] packs elements {2w,2w+1} = c1[2s+(w>>1)][(w&1)*2 + {0,1}]
            short8 pb[2];
            #pragma unroll
            for (int s = 0; s < 2; ++s) {
                union { short8 s8; unsigned u[4]; } P;
                #pragma unroll
                for (int w = 0; w < 4; ++w) {
                    float lo = silu_pre(c1[2 * s + (w >> 1)][(w & 1) * 2 + 0]);
                    float hi = silu_pre(c1[2 * s + (w >> 1)][(w & 1) * 2 + 1]);
                    P.u[w] = pk2(lo, hi);
                }
                pb[s] = P.s8;
            }

            f32x4 c2a[4];
            #pragma unroll
            for (int mt = 0; mt < 4; ++mt) {
                f32x4 acc = __builtin_amdgcn_mfma_f32_16x16x32_bf16(Wlds[4 + 2 * mt + 0][lane], pb[0], bias2[mt], 0, 0, 0);
                acc       = __builtin_amdgcn_mfma_f32_16x16x32_bf16(Wlds[4 + 2 * mt + 1][lane], pb[1], acc,       0, 0, 0);
                c2a[mt] = acc;
            }

            short8 qb[2];
            #pragma unroll
            for (int s = 0; s < 2; ++s) {
                union { short8 s8; unsigned u[4]; } Q;
                #pragma unroll
                for (int w = 0; w < 4; ++w) {
                    float lo = silu_pre(c2a[2 * s + (w >> 1)][(w & 1) * 2 + 0]);
                    float hi = silu_pre(c2a[2 * s + (w >> 1)][(w & 1) * 2 + 1]);
                    Q.u[w] = pk2(lo, hi);
                }
                qb[s] = Q.s8;
            }

            f32x4 c3 = __builtin_amdgcn_mfma_f32_16x16x32_bf16(Wlds[12][lane], qb[0], c3i, 0, 0, 0);
            c3       = __builtin_amdgcn_mfma_f32_16x16x32_bf16(Wlds[13][lane], qb[1], c3,  0, 0, 0);

            if (g16 == 0) {
                int ob = idxs[row];
                atomicAdd(&out[ob + 0], c3[0]);
                atomicAdd(&out[ob + 1], c3[1]);
            }
        }
        barrier_lds();
    }
}

extern "C" void kernel_launch(void* const* d_in, const int* in_sizes, int n_in,
                              void* d_out, int out_size, void* d_ws, size_t ws_size,
                              hipStream_t stream) {
    const float* x     = (const float*)d_in[0];
    const float* theta = (const float*)d_in[1];
    const float* H     = (const float*)d_in[2];
    const int*   ei    = (const int*)d_in[3];
    const float* W1    = (const float*)d_in[4];
    const float* b1    = (const float*)d_in[5];
    const float* W2    = (const float*)d_in[6];
    const float* b2    = (const float*)d_in[7];
    const float* W3    = (const float*)d_in[8];
    const float* b3    = (const float*)d_in[9];
    float* out = (float*)d_out;

    hipMemsetAsync(d_out, 0, (size_t)out_size * sizeof(float), stream);

    int* flag = (int*)d_ws;
    detect_idx_kernel<<<1, 64, 0, stream>>>(ei, flag);

    gnn_mfma_kernel<<<GRID, 256, 0, stream>>>(x, theta, H, ei,
                                              W1, b1, W2, b2, W3, b3,
                                              out, flag);
}

// Round 12
// 120.692 us; speedup vs baseline: 1.0309x; 1.0309x over previous
//
#include <hip/hip_runtime.h>

#define EDGES 800000
#define GROUPS 10           // edge-groups per block
#define EPB (GROUPS * 64)   // edges per block = 640; 1250 blocks exactly

#define LOG2E 1.44269504089f
#define LN2   0.69314718056f

typedef __attribute__((ext_vector_type(8))) short short8;
typedef __attribute__((ext_vector_type(4))) float f32x4;

__device__ __forceinline__ unsigned short f2bf(float f) {   // cold path (weights)
    union { float f; unsigned u; } c; c.f = f;
    return (unsigned short)((c.u + 0x7FFFu + ((c.u >> 16) & 1u)) >> 16);
}

// packed bf16 pair: one v_cvt_pk_bf16_f32 -> u32 word {lo, hi}
__device__ __forceinline__ unsigned pk2(float lo, float hi) {
    unsigned r;
    asm("v_cvt_pk_bf16_f32 %0, %1, %2" : "=v"(r) : "v"(lo), "v"(hi));
    return r;
}

// u = t*log2e (weights prescaled). Returns log2e*silu(t) = u*sigmoid(t).
__device__ __forceinline__ float silu_pre(float u) {
    return u * __builtin_amdgcn_rcpf(1.0f + __builtin_amdgcn_exp2f(-u));
}

// Barrier waiting only on LDS ops (atomics may stay in flight) — R9 win.
__device__ __forceinline__ void barrier_lds() {
    asm volatile("s_waitcnt lgkmcnt(0)\n\ts_barrier" ::: "memory");
}

// fast atan2: A&S 4.4.49 poly, |err| <= ~1e-5; atan2(0,0) -> 0 like numpy
__device__ __forceinline__ float fast_atan2f(float y, float x) {
    float ax = __builtin_fabsf(x), ay = __builtin_fabsf(y);
    float mx = fmaxf(ax, ay), mn = fminf(ax, ay);
    float z  = mn * __builtin_amdgcn_rcpf(mx);
    float z2 = z * z;
    float p  = fmaf(z2, 0.0208351f, -0.0851330f);
    p = fmaf(z2, p, 0.1801410f);
    p = fmaf(z2, p, -0.3302995f);
    p = fmaf(z2, p, 0.9998660f);
    float t = z * p;
    t = (ay > ax)   ? 1.57079632679f - t : t;
    t = (x < 0.0f)  ? 3.14159265359f - t : t;
    t = (y < 0.0f)  ? -t : t;
    return (mx > 0.0f) ? t : 0.0f;
}

// flag: 1 = int32 edge_index layout, 0 = int64 (low words at even positions)
__global__ void detect_idx_kernel(const int* __restrict__ ei, int* __restrict__ flag) {
    int t = threadIdx.x;
    int v = 0;
    for (int k = t; k < 2048; k += 64) v |= ei[2 * k + 1];
    unsigned long long m = __ballot(v != 0);
    if (t == 0) flag[0] = (m != 0ull) ? 1 : 0;
}

__global__ __launch_bounds__(256, 4) void gnn_mfma_kernel(
    const float* __restrict__ x, const float* __restrict__ theta,
    const float* __restrict__ H, const int* __restrict__ ei,
    const float* __restrict__ W1, const float* __restrict__ b1,
    const float* __restrict__ W2, const float* __restrict__ b2,
    const float* __restrict__ W3, const float* __restrict__ b3,
    float* __restrict__ out, const int* __restrict__ flag)
{
    // 8 KB: 256 rows x 16 bf16 (k=0..15 only; k=16..31 are synthesized zeros
    // in registers — their W rows are zero too, so the MFMA result is exact).
    __shared__ unsigned short Xs[256 * 16];
    __shared__ int idxs[256];                // out base per row
    // Weight fragments, lane-indexed (conflict-free ds_read_b128).
    // f: 0..3=W1, 4..11=W2[mt][s], 12..13=W3.
    __shared__ short8 Wlds[14][64];          // 14 KB

    const int t    = threadIdx.x;
    const int lane = t & 63;
    const int wv   = t >> 6;
    const int g16  = lane >> 4;
    const int l15  = lane & 15;
    const bool idx32 = (flag[0] != 0);

    // ---------- weight fragments -> LDS (cold; wave 0 only), PRESCALED ----------
    // W1,b1 *= log2e ; W2 unchanged (ln2*log2e = 1) ; b2 *= log2e ;
    // W3 *= ln2 ; b3 unchanged.  (verified exact R5/R7/R9/R10)
    if (wv == 0) {
        #pragma unroll
        for (int nt = 0; nt < 4; ++nt) {
            short8 v;
            #pragma unroll
            for (int j = 0; j < 8; ++j) {
                int k = 8 * g16 + j;
                int h = nt * 16 + l15;
                float w = 0.0f;
                if (k < 10)       w = W1[k * 64 + h] * LOG2E;
                else if (k == 10) w = b1[h] * LOG2E;
                v[j] = (short)f2bf(w);
            }
            Wlds[nt][lane] = v;
        }
        // physical k-slot p = 32s + 8g + j holds logical unit
        //   lambda(p) = 16*(2s + (j>>2)) + 4g + (j&3)
        #pragma unroll
        for (int mt = 0; mt < 4; ++mt) {
            #pragma unroll
            for (int s = 0; s < 2; ++s) {
                short8 v;
                #pragma unroll
                for (int j = 0; j < 8; ++j) {
                    int h1 = 16 * (2 * s + (j >> 2)) + 4 * g16 + (j & 3);
                    int h2 = 16 * mt + l15;
                    v[j] = (short)f2bf(W2[h1 * 64 + h2]);
                }
                Wlds[4 + 2 * mt + s][lane] = v;
            }
        }
        #pragma unroll
        for (int s = 0; s < 2; ++s) {
            short8 v;
            #pragma unroll
            for (int j = 0; j < 8; ++j) {
                int h2 = 16 * (2 * s + (j >> 2)) + 4 * g16 + (j & 3);
                float w = (l15 < 2) ? W3[h2 * 2 + l15] * LN2 : 0.0f;
                v[j] = (short)f2bf(w);
            }
            Wlds[12 + s][lane] = v;
        }
    }
    f32x4 bias2[4];
    #pragma unroll
    for (int mt = 0; mt < 4; ++mt) {
        #pragma unroll
        for (int r = 0; r < 4; ++r)
            bias2[mt][r] = b2[16 * mt + 4 * g16 + r] * LOG2E;
    }
    f32x4 c3i;
    #pragma unroll
    for (int r = 0; r < 4; ++r) {
        int o = 4 * g16 + r;
        c3i[r] = (o == 0) ? b3[0] : ((o == 1) ? b3[1] : 0.0f);
    }
    barrier_lds();

    for (int grp = 0; grp < GROUPS; ++grp) {
        const int e0 = blockIdx.x * EPB + grp * 64;

        // ---------- phase 1: geometry, one (edge,slot) row per thread ----------
        {
            int el = t >> 2, slot = t & 3;
            int e = e0 + el;
            int i, j;
            if (idx32) { i = ei[e];     j = ei[EDGES + e]; }
            else       { i = ei[2 * e]; j = ei[2 * EDGES + 2 * e]; }

            float dx0 = x[3 * j + 0] - x[3 * i + 0];
            float dx1 = x[3 * j + 1] - x[3 * i + 1];
            float dz  = x[3 * j + 2] - x[3 * i + 2];
            float rxy2 = dx0 * dx0 + dx1 * dx1;
            float r3d  = __builtin_amdgcn_sqrtf(rxy2 + dz * dz);
            float rxy  = __builtin_amdgcn_sqrtf(rxy2);
            float phi  = fast_atan2f(dx1, dx0);
            float ti = theta[i], tj = theta[j];
            float dphi = phi - ti;
            float sdp = __sinf(dphi), cdp = __cosf(dphi);
            float dt2 = 2.0f * (tj - ti);
            float s2 = __sinf(dt2), c2 = __cosf(dt2);
            float g7 = (dz > 0.0f) ? s2 : ((dz < 0.0f) ? -s2 : 0.0f);

            float2 hv = *(const float2*)&H[((long)j * 4 + slot) * 2];
            float in0 = c2 * hv.x - s2 * hv.y;
            float in1 = s2 * hv.x + c2 * hv.y;

            union { short8 s8; unsigned u[4]; } A, B;
            A.u[0] = pk2(in0, in1);
            A.u[1] = pk2(r3d, rxy);
            A.u[2] = pk2(dz, sdp);
            A.u[3] = pk2(cdp, s2);
            B.u[0] = pk2(c2, g7);
            B.u[1] = 0x00003F80u;   // {1.0bf, 0}
            B.u[2] = 0; B.u[3] = 0;

            int row = t;
            *(short8*)(&Xs[row * 16 + 0]) = A.s8;   // k = 0..7
            *(short8*)(&Xs[row * 16 + 8]) = B.s8;   // k = 8..15
            idxs[row] = i * 8 + slot * 2;
        }
        barrier_lds();

        // ---------- phase 2: 4 M-tiles of 16 edge-rows per wave ----------
        #pragma unroll
        for (int tt = 0; tt < 4; ++tt) {
            int row = wv * 64 + tt * 16 + l15;
            short8 xb;
            #pragma unroll
            for (int q = 0; q < 8; ++q) xb[q] = 0;
            if (g16 < 2)   // k=16..31 fragment is identically zero
                xb = *(const short8*)(&Xs[row * 16 + g16 * 8]);

            f32x4 z4 = {0.0f, 0.0f, 0.0f, 0.0f};
            f32x4 c1[4];
            #pragma unroll
            for (int nt = 0; nt < 4; ++nt)
                c1[nt] = __builtin_amdgcn_mfma_f32_16x16x32_bf16(Wlds[nt][lane], xb, z4, 0, 0, 0);

            // word w of pb[s] packs elements {2w,2w+1} = c1[2s+(w>>1)][(w&1)*2 + {0,1}]
            short8 pb[2];
            #pragma unroll
            for (int s = 0; s < 2; ++s) {
                union { short8 s8; unsigned u[4]; } P;
                #pragma unroll
                for (int w = 0; w < 4; ++w) {
                    float lo = silu_pre(c1[2 * s + (w >> 1)][(w & 1) * 2 + 0]);
                    float hi = silu_pre(c1[2 * s + (w >> 1)][(w & 1) * 2 + 1]);
                    P.u[w] = pk2(lo, hi);
                }
                pb[s] = P.s8;
            }

            f32x4 c2a[4];
            #pragma unroll
            for (int mt = 0; mt < 4; ++mt) {
                f32x4 acc = __builtin_amdgcn_mfma_f32_16x16x32_bf16(Wlds[4 + 2 * mt + 0][lane], pb[0], bias2[mt], 0, 0, 0);
                acc       = __builtin_amdgcn_mfma_f32_16x16x32_bf16(Wlds[4 + 2 * mt + 1][lane], pb[1], acc,       0, 0, 0);
                c2a[mt] = acc;
            }

            short8 qb[2];
            #pragma unroll
            for (int s = 0; s < 2; ++s) {
                union { short8 s8; unsigned u[4]; } Q;
                #pragma unroll
                for (int w = 0; w < 4; ++w) {
                    float lo = silu_pre(c2a[2 * s + (w >> 1)][(w & 1) * 2 + 0]);
                    float hi = silu_pre(c2a[2 * s + (w >> 1)][(w & 1) * 2 + 1]);
                    Q.u[w] = pk2(lo, hi);
                }
                qb[s] = Q.s8;
            }

            f32x4 c3 = __builtin_amdgcn_mfma_f32_16x16x32_bf16(Wlds[12][lane], qb[0], c3i, 0, 0, 0);
            c3       = __builtin_amdgcn_mfma_f32_16x16x32_bf16(Wlds[13][lane], qb[1], c3,  0, 0, 0);

            if (g16 == 0) {
                int ob = idxs[row];
                atomicAdd(&out[ob + 0], c3[0]);
                atomicAdd(&out[ob + 1], c3[1]);
            }
        }
        barrier_lds();
    }
}

extern "C" void kernel_launch(void* const* d_in, const int* in_sizes, int n_in,
                              void* d_out, int out_size, void* d_ws, size_t ws_size,
                              hipStream_t stream) {
    const float* x     = (const float*)d_in[0];
    const float* theta = (const float*)d_in[1];
    const float* H     = (const float*)d_in[2];
    const int*   ei    = (const int*)d_in[3];
    const float* W1    = (const float*)d_in[4];
    const float* b1    = (const float*)d_in[5];
    const float* W2    = (const float*)d_in[6];
    const float* b2    = (const float*)d_in[7];
    const float* W3    = (const float*)d_in[8];
    const float* b3    = (const float*)d_in[9];
    float* out = (float*)d_out;

    hipMemsetAsync(d_out, 0, (size_t)out_size * sizeof(float), stream);

    int* flag = (int*)d_ws;
    detect_idx_kernel<<<1, 64, 0, stream>>>(ei, flag);

    gnn_mfma_kernel<<<EDGES / EPB, 256, 0, stream>>>(x, theta, H, ei,
                                                     W1, b1, W2, b2, W3, b3,
                                                     out, flag);
}

// Round 13
// 119.903 us; speedup vs baseline: 1.0377x; 1.0066x over previous
//
#include <hip/hip_runtime.h>

#define EDGES 800000
#define GROUPS 10           // edge-groups per block
#define EPB (GROUPS * 64)   // edges per block = 640; 1250 blocks exactly

#define LOG2E 1.44269504089f
#define LN2   0.69314718056f

typedef __attribute__((ext_vector_type(8))) short short8;
typedef __attribute__((ext_vector_type(4))) float f32x4;

__device__ __forceinline__ unsigned short f2bf(float f) {   // cold path (weights)
    union { float f; unsigned u; } c; c.f = f;
    return (unsigned short)((c.u + 0x7FFFu + ((c.u >> 16) & 1u)) >> 16);
}

// packed bf16 pair: one v_cvt_pk_bf16_f32 -> u32 word {lo, hi}
__device__ __forceinline__ unsigned pk2(float lo, float hi) {
    unsigned r;
    asm("v_cvt_pk_bf16_f32 %0, %1, %2" : "=v"(r) : "v"(lo), "v"(hi));
    return r;
}

// u = t*log2e (weights prescaled). Returns log2e*silu(t) = u*sigmoid(t).
__device__ __forceinline__ float silu_pre(float u) {
    return u * __builtin_amdgcn_rcpf(1.0f + __builtin_amdgcn_exp2f(-u));
}

// Full block barrier (used once, after Wlds cold stage) — R9 lgkm-only form.
__device__ __forceinline__ void barrier_lds() {
    asm volatile("s_waitcnt lgkmcnt(0)\n\ts_barrier" ::: "memory");
}

// Wave-local LDS fence: phase1->phase2 dataflow is WAVE-INTERNAL (wave wv's
// lanes write rows [wv*64, wv*64+64) and read exactly those rows), so no
// s_barrier is needed — only completion of this wave's DS ops.
__device__ __forceinline__ void fence_lds_wave() {
    asm volatile("s_waitcnt lgkmcnt(0)" ::: "memory");
}

// fast atan2: A&S 4.4.49 poly, |err| <= ~1e-5; atan2(0,0) -> 0 like numpy
__device__ __forceinline__ float fast_atan2f(float y, float x) {
    float ax = __builtin_fabsf(x), ay = __builtin_fabsf(y);
    float mx = fmaxf(ax, ay), mn = fminf(ax, ay);
    float z  = mn * __builtin_amdgcn_rcpf(mx);
    float z2 = z * z;
    float p  = fmaf(z2, 0.0208351f, -0.0851330f);
    p = fmaf(z2, p, 0.1801410f);
    p = fmaf(z2, p, -0.3302995f);
    p = fmaf(z2, p, 0.9998660f);
    float t = z * p;
    t = (ay > ax)   ? 1.57079632679f - t : t;
    t = (x < 0.0f)  ? 3.14159265359f - t : t;
    t = (y < 0.0f)  ? -t : t;
    return (mx > 0.0f) ? t : 0.0f;
}

// flag: 1 = int32 edge_index layout, 0 = int64 (low words at even positions)
__global__ void detect_idx_kernel(const int* __restrict__ ei, int* __restrict__ flag) {
    int t = threadIdx.x;
    int v = 0;
    for (int k = t; k < 2048; k += 64) v |= ei[2 * k + 1];
    unsigned long long m = __ballot(v != 0);
    if (t == 0) flag[0] = (m != 0ull) ? 1 : 0;
}

__global__ __launch_bounds__(256, 4) void gnn_mfma_kernel(
    const float* __restrict__ x, const float* __restrict__ theta,
    const float* __restrict__ H, const int* __restrict__ ei,
    const float* __restrict__ W1, const float* __restrict__ b1,
    const float* __restrict__ W2, const float* __restrict__ b2,
    const float* __restrict__ W3, const float* __restrict__ b3,
    float* __restrict__ out, const int* __restrict__ flag)
{
    // 8 KB: 256 rows x 16 bf16 (k=0..15; k=16..31 synthesized zeros in regs).
    __shared__ unsigned short Xs[256 * 16];
    __shared__ int idxs[256];                // out base per row
    // Weight fragments, lane-indexed (conflict-free ds_read_b128).
    // f: 0..3=W1, 4..11=W2[mt][s], 12..13=W3.
    __shared__ short8 Wlds[14][64];          // 14 KB

    const int t    = threadIdx.x;
    const int lane = t & 63;
    const int wv   = t >> 6;
    const int g16  = lane >> 4;
    const int l15  = lane & 15;
    const bool idx32 = (flag[0] != 0);

    // ---------- weight fragments -> LDS (cold; wave 0 only), PRESCALED ----------
    // W1,b1 *= log2e ; W2 unchanged (ln2*log2e = 1) ; b2 *= log2e ;
    // W3 *= ln2 ; b3 unchanged.  (verified exact R5/R7/R9/R10)
    if (wv == 0) {
        #pragma unroll
        for (int nt = 0; nt < 4; ++nt) {
            short8 v;
            #pragma unroll
            for (int j = 0; j < 8; ++j) {
                int k = 8 * g16 + j;
                int h = nt * 16 + l15;
                float w = 0.0f;
                if (k < 10)       w = W1[k * 64 + h] * LOG2E;
                else if (k == 10) w = b1[h] * LOG2E;
                v[j] = (short)f2bf(w);
            }
            Wlds[nt][lane] = v;
        }
        // physical k-slot p = 32s + 8g + j holds logical unit
        //   lambda(p) = 16*(2s + (j>>2)) + 4g + (j&3)
        #pragma unroll
        for (int mt = 0; mt < 4; ++mt) {
            #pragma unroll
            for (int s = 0; s < 2; ++s) {
                short8 v;
                #pragma unroll
                for (int j = 0; j < 8; ++j) {
                    int h1 = 16 * (2 * s + (j >> 2)) + 4 * g16 + (j & 3);
                    int h2 = 16 * mt + l15;
                    v[j] = (short)f2bf(W2[h1 * 64 + h2]);
                }
                Wlds[4 + 2 * mt + s][lane] = v;
            }
        }
        #pragma unroll
        for (int s = 0; s < 2; ++s) {
            short8 v;
            #pragma unroll
            for (int j = 0; j < 8; ++j) {
                int h2 = 16 * (2 * s + (j >> 2)) + 4 * g16 + (j & 3);
                float w = (l15 < 2) ? W3[h2 * 2 + l15] * LN2 : 0.0f;
                v[j] = (short)f2bf(w);
            }
            Wlds[12 + s][lane] = v;
        }
    }
    f32x4 bias2[4];
    #pragma unroll
    for (int mt = 0; mt < 4; ++mt) {
        #pragma unroll
        for (int r = 0; r < 4; ++r)
            bias2[mt][r] = b2[16 * mt + 4 * g16 + r] * LOG2E;
    }
    f32x4 c3i;
    #pragma unroll
    for (int r = 0; r < 4; ++r) {
        int o = 4 * g16 + r;
        c3i[r] = (o == 0) ? b3[0] : ((o == 1) ? b3[1] : 0.0f);
    }
    barrier_lds();   // the ONLY block-wide barrier: Wlds ready for all waves

    for (int grp = 0; grp < GROUPS; ++grp) {
        const int e0 = blockIdx.x * EPB + grp * 64;

        // ---------- phase 1: geometry, one (edge,slot) row per thread ----------
        {
            int el = t >> 2, slot = t & 3;
            int e = e0 + el;
            int i, j;
            if (idx32) { i = ei[e];     j = ei[EDGES + e]; }
            else       { i = ei[2 * e]; j = ei[2 * EDGES + 2 * e]; }

            float dx0 = x[3 * j + 0] - x[3 * i + 0];
            float dx1 = x[3 * j + 1] - x[3 * i + 1];
            float dz  = x[3 * j + 2] - x[3 * i + 2];
            float rxy2 = dx0 * dx0 + dx1 * dx1;
            float r3d  = __builtin_amdgcn_sqrtf(rxy2 + dz * dz);
            float rxy  = __builtin_amdgcn_sqrtf(rxy2);
            float phi  = fast_atan2f(dx1, dx0);
            float ti = theta[i], tj = theta[j];
            float dphi = phi - ti;
            float sdp = __sinf(dphi), cdp = __cosf(dphi);
            float dt2 = 2.0f * (tj - ti);
            float s2 = __sinf(dt2), c2 = __cosf(dt2);
            float g7 = (dz > 0.0f) ? s2 : ((dz < 0.0f) ? -s2 : 0.0f);

            float2 hv = *(const float2*)&H[((long)j * 4 + slot) * 2];
            float in0 = c2 * hv.x - s2 * hv.y;
            float in1 = s2 * hv.x + c2 * hv.y;

            union { short8 s8; unsigned u[4]; } A, B;
            A.u[0] = pk2(in0, in1);
            A.u[1] = pk2(r3d, rxy);
            A.u[2] = pk2(dz, sdp);
            A.u[3] = pk2(cdp, s2);
            B.u[0] = pk2(c2, g7);
            B.u[1] = 0x00003F80u;   // {1.0bf, 0}
            B.u[2] = 0; B.u[3] = 0;

            int row = t;
            *(short8*)(&Xs[row * 16 + 0]) = A.s8;   // k = 0..7
            *(short8*)(&Xs[row * 16 + 8]) = B.s8;   // k = 8..15
            idxs[row] = i * 8 + slot * 2;
        }
        fence_lds_wave();   // own-wave writes visible to own-wave reads

        // ---------- phase 2: 4 M-tiles of 16 edge-rows per wave ----------
        #pragma unroll
        for (int tt = 0; tt < 4; ++tt) {
            int row = wv * 64 + tt * 16 + l15;   // rows this wave itself wrote
            short8 xb;
            #pragma unroll
            for (int q = 0; q < 8; ++q) xb[q] = 0;
            if (g16 < 2)   // k=16..31 fragment is identically zero
                xb = *(const short8*)(&Xs[row * 16 + g16 * 8]);

            f32x4 z4 = {0.0f, 0.0f, 0.0f, 0.0f};
            f32x4 c1[4];
            #pragma unroll
            for (int nt = 0; nt < 4; ++nt)
                c1[nt] = __builtin_amdgcn_mfma_f32_16x16x32_bf16(Wlds[nt][lane], xb, z4, 0, 0, 0);

            // word w of pb[s] packs elements {2w,2w+1} = c1[2s+(w>>1)][(w&1)*2 + {0,1}]
            short8 pb[2];
            #pragma unroll
            for (int s = 0; s < 2; ++s) {
                union { short8 s8; unsigned u[4]; } P;
                #pragma unroll
                for (int w = 0; w < 4; ++w) {
                    float lo = silu_pre(c1[2 * s + (w >> 1)][(w & 1) * 2 + 0]);
                    float hi = silu_pre(c1[2 * s + (w >> 1)][(w & 1) * 2 + 1]);
                    P.u[w] = pk2(lo, hi);
                }
                pb[s] = P.s8;
            }

            f32x4 c2a[4];
            #pragma unroll
            for (int mt = 0; mt < 4; ++mt) {
                f32x4 acc = __builtin_amdgcn_mfma_f32_16x16x32_bf16(Wlds[4 + 2 * mt + 0][lane], pb[0], bias2[mt], 0, 0, 0);
                acc       = __builtin_amdgcn_mfma_f32_16x16x32_bf16(Wlds[4 + 2 * mt + 1][lane], pb[1], acc,       0, 0, 0);
                c2a[mt] = acc;
            }

            short8 qb[2];
            #pragma unroll
            for (int s = 0; s < 2; ++s) {
                union { short8 s8; unsigned u[4]; } Q;
                #pragma unroll
                for (int w = 0; w < 4; ++w) {
                    float lo = silu_pre(c2a[2 * s + (w >> 1)][(w & 1) * 2 + 0]);
                    float hi = silu_pre(c2a[2 * s + (w >> 1)][(w & 1) * 2 + 1]);
                    Q.u[w] = pk2(lo, hi);
                }
                qb[s] = Q.s8;
            }

            f32x4 c3 = __builtin_amdgcn_mfma_f32_16x16x32_bf16(Wlds[12][lane], qb[0], c3i, 0, 0, 0);
            c3       = __builtin_amdgcn_mfma_f32_16x16x32_bf16(Wlds[13][lane], qb[1], c3,  0, 0, 0);

            if (g16 == 0) {
                int ob = idxs[row];
                atomicAdd(&out[ob + 0], c3[0]);
                atomicAdd(&out[ob + 1], c3[1]);
            }
        }
        fence_lds_wave();   // WAR: this wave's reads done before next group's writes
    }
}

extern "C" void kernel_launch(void* const* d_in, const int* in_sizes, int n_in,
                              void* d_out, int out_size, void* d_ws, size_t ws_size,
                              hipStream_t stream) {
    const float* x     = (const float*)d_in[0];
    const float* theta = (const float*)d_in[1];
    const float* H     = (const float*)d_in[2];
    const int*   ei    = (const int*)d_in[3];
    const float* W1    = (const float*)d_in[4];
    const float* b1    = (const float*)d_in[5];
    const float* W2    = (const float*)d_in[6];
    const float* b2    = (const float*)d_in[7];
    const float* W3    = (const float*)d_in[8];
    const float* b3    = (const float*)d_in[9];
    float* out = (float*)d_out;

    hipMemsetAsync(d_out, 0, (size_t)out_size * sizeof(float), stream);

    int* flag = (int*)d_ws;
    detect_idx_kernel<<<1, 64, 0, stream>>>(ei, flag);

    gnn_mfma_kernel<<<EDGES / EPB, 256, 0, stream>>>(x, theta, H, ei,
                                                     W1, b1, W2, b2, W3, b3,
                                                     out, flag);
}